// Round 4
// baseline (14999.673 us; speedup 1.0000x reference)
//
#include <hip/hip_runtime.h>

#define Bsz  4
#define Lsz  4096
#define Csz  1024
#define NHsz 16
#define CSsz 16
#define HFsz 64
#define HF4sz 256
#define NCsz 256

// ---------------------------------------------------------------------------
// fp32 GEMM: C[M,N] = A[M,K] @ B[K,N].  64x64 tile, BK=16, 4x4 microtile.
// ---------------------------------------------------------------------------
__global__ __launch_bounds__(256)
void gemm64(const float* __restrict__ A, const float* __restrict__ Bm,
            float* __restrict__ Cm, int M, int N, int K)
{
  __shared__ __attribute__((aligned(16))) float As[16][68];
  __shared__ __attribute__((aligned(16))) float Bs[16][64];
  const int t  = threadIdx.x;
  const int tx = t & 15, ty = t >> 4;
  const int row0 = blockIdx.y * 64, col0 = blockIdx.x * 64;
  const int ar = t >> 2, ak = (t & 3) * 4;
  const int bk = t >> 4, bc = (t & 15) * 4;
  float acc[4][4] = {};

  for (int k0 = 0; k0 < K; k0 += 16) {
    float4 a4 = *(const float4*)&A[(size_t)(row0 + ar) * K + k0 + ak];
    float4 b4 = *(const float4*)&Bm[(size_t)(k0 + bk) * N + col0 + bc];
    As[ak + 0][ar] = a4.x; As[ak + 1][ar] = a4.y;
    As[ak + 2][ar] = a4.z; As[ak + 3][ar] = a4.w;
    *(float4*)&Bs[bk][bc] = b4;
    __syncthreads();
#pragma unroll
    for (int kk = 0; kk < 16; ++kk) {
      float4 av = *(const float4*)&As[kk][ty * 4];
      float4 bv = *(const float4*)&Bs[kk][tx * 4];
      acc[0][0] += av.x * bv.x; acc[0][1] += av.x * bv.y;
      acc[0][2] += av.x * bv.z; acc[0][3] += av.x * bv.w;
      acc[1][0] += av.y * bv.x; acc[1][1] += av.y * bv.y;
      acc[1][2] += av.y * bv.z; acc[1][3] += av.y * bv.w;
      acc[2][0] += av.z * bv.x; acc[2][1] += av.z * bv.y;
      acc[2][2] += av.z * bv.z; acc[2][3] += av.z * bv.w;
      acc[3][0] += av.w * bv.x; acc[3][1] += av.w * bv.y;
      acc[3][2] += av.w * bv.z; acc[3][3] += av.w * bv.w;
    }
    __syncthreads();
  }
#pragma unroll
  for (int r = 0; r < 4; ++r) {
    float4 v = make_float4(acc[r][0], acc[r][1], acc[r][2], acc[r][3]);
    *(float4*)&Cm[(size_t)(row0 + ty * 4 + r) * N + col0 + tx * 4] = v;
  }
}

// ---------------------------------------------------------------------------
// ilr -> coeff table
// ---------------------------------------------------------------------------
__global__ __launch_bounds__(256)
void ilr_coeff(const float* __restrict__ H, const float* __restrict__ Wil,
               const float* __restrict__ bil, float* __restrict__ coeff)
{
  __shared__ float sRow[4][1024];
  __shared__ float sP[4][16][17];
  const int t = threadIdx.x;
  const size_t r0 = (size_t)blockIdx.x * 4;
  for (int rr = 0; rr < 4; ++rr)
    for (int c = t; c < 1024; c += 256)
      sRow[rr][c] = H[(r0 + rr) * 1024 + c];
  __syncthreads();
  const int hh = t & 15, sl = t >> 4;
  for (int rr = 0; rr < 4; ++rr) {
    float acc = 0.f;
    for (int kk = 0; kk < 64; ++kk)
      acc += sRow[rr][sl * 64 + kk] * Wil[(sl * 64 + kk) * 16 + hh];
    sP[rr][sl][hh] = acc;
  }
  __syncthreads();
  if (t < 64) {
    const int rr = t >> 4, h2 = t & 15;
    float s = 0.f;
    for (int sl2 = 0; sl2 < 16; ++sl2) s += sP[rr][sl2][h2];
    s += bil[h2];
    const float sig = 1.f / (1.f + expf(-s));
    const int r  = (int)(r0 + rr);
    const int b  = r >> 12, l = r & 4095, nc = l >> 4, cs = l & 15;
    coeff[((b * 16 + h2) * NCsz + nc) * CSsz + cs] = sig / ((float)(cs + 1) * 64.0f);
  }
}

// ---------------------------------------------------------------------------
// TTT scan, wave-specialized + prefetched.  One block per (b,h); 512 threads.
//   A-group (t<256):  w1[64] = W1[k][n], n = t.
//   B-group (t>=256): w2r[64] = W2[n][mm]  (n = t&255, row copy)
//                     w2c[64] = W2[q*64+kk][m]  (wave-local quads:
//                       lane=t&63, ml=lane&15, q=lane>>4, m=(t>>6&3)*16+ml)
// 6 barriers/chunk.  Z2/Z2b k-quad reduction is wave-local (__shfl_xor).
// XB/XC/XA/coeff for chunk nc+1 prefetched into regs at P1(nc), written to
// LDS at P3 (XC) and P5 (XB, XA) when the old copies are dead.
// sBIG overlays three disjoint live ranges:
//   g1[16][256]  : written P3, read P4
//   A2[0,256)    : written P5, read P6
//   XA[256,1280) : written P5(nc), read P2(nc+1)
// sZ1 row stride 276, sZ1b 272; k stored at (k>>6)*68+(k&63) within a row
// (quad offsets 0/68/136/204 -> conflict-free quad reads; 17/69-style bank
// spreading for row reads).
// ---------------------------------------------------------------------------
__global__ __launch_bounds__(512, 2)
void ttt_scan(const float* __restrict__ XA, const float* __restrict__ XBuf,
              const float* __restrict__ XCbuf, const float* __restrict__ coeff,
              const float* __restrict__ W1g, const float* __restrict__ W2g,
              float* __restrict__ Out)
{
  __shared__ __attribute__((aligned(16))) float sXB[16 * 68];
  __shared__ __attribute__((aligned(16))) float sXC[16 * 68];
  __shared__ __attribute__((aligned(16))) float sg2[16 * 64];
  __shared__ __attribute__((aligned(16))) float sZ1[16 * 276];
  __shared__ __attribute__((aligned(16))) float sZ1b[16 * 272];
  __shared__ __attribute__((aligned(16))) float sBIG[4096];
  __shared__ float sA1[256];
  __shared__ float sCo[16];

  const int t    = threadIdx.x;
  const int bh   = blockIdx.x;
  const int b    = bh >> 4, h = bh & 15;
  const bool isA = (t < 256);
  const int n    = t & 255;
  const int lane = t & 63;
  const int ml   = lane & 15, q = lane >> 4, wv = (t >> 6) & 3;
  const int m    = wv * 16 + ml;                 // B: HF column
  const int offn = ((n >> 6) * 68) + (n & 63);   // quad-layout offset for col n
  const int ia   = n >> 4, ja = n & 15;

  float w1[64];            // A only
  float w2r[64], w2c[64];  // B only
  float z1bR[16];          // A: Z1b pre/final (column n)
  float z2bF[16];          // B: Z2b pre-attn  (column m)

  const float* W1h = W1g + h * HFsz * HF4sz;
  const float* W2h = W2g + h * HF4sz * HFsz;
  if (isA) {
#pragma unroll
    for (int k = 0; k < 64; ++k) w1[k] = W1h[k * 256 + n];
  } else {
#pragma unroll
    for (int mm = 0; mm < 64; ++mm) w2r[mm] = W2h[n * 64 + mm];
#pragma unroll
    for (int kk = 0; kk < 64; ++kk) w2c[kk] = W2h[(q * 64 + kk) * 64 + m];
  }

  // prefetch registers (A only)
  float4 xbP, xcP, xaP;
  float coP = 0.f;
  const int prow = n >> 4, pcol = (n & 15) * 4;

  // ---- prologue: stage chunk 0 ------------------------------------------
  {
    const int cb0 = (b * Lsz) * Csz + h * HFsz;
    if (isA) {
      xbP = *(const float4*)&XBuf[cb0 + prow * 1024 + pcol];
      xcP = *(const float4*)&XCbuf[cb0 + prow * 1024 + pcol];
      xaP = *(const float4*)&XA[cb0 + prow * 1024 + pcol];
      if (t < 16) coP = coeff[(bh * NCsz) * CSsz + t];
      *(float4*)&sXB[prow * 68 + pcol] = xbP;
      *(float4*)&sXC[prow * 68 + pcol] = xcP;
      *(float4*)&sBIG[256 + prow * 64 + pcol] = xaP;
    }
  }
  __syncthreads();

#pragma unroll 1
  for (int nc = 0; nc < NCsz; ++nc) {
    const int cb  = (b * Lsz + nc * CSsz) * Csz + h * HFsz;
    const int ncn = (nc + 1) & 255;  // wrap at end: loads valid, values unused
    const int cbn = (b * Lsz + ncn * CSsz) * Csz + h * HFsz;

    // ---- P1: A: sCo write, prefetch issue, Z1 -> sZ1 | B: Attn1 ---------
    if (isA) {
      if (t < 16) sCo[t] = coP;
      xbP = *(const float4*)&XBuf[cbn + prow * 1024 + pcol];
      xcP = *(const float4*)&XCbuf[cbn + prow * 1024 + pcol];
      xaP = *(const float4*)&XA[cbn + prow * 1024 + pcol];
      if (t < 16) coP = coeff[(bh * NCsz + ncn) * CSsz + t];
#pragma unroll
      for (int i = 0; i < 16; ++i) {
        float acc = 0.f;
#pragma unroll
        for (int k = 0; k < 64; k += 4) {
          float4 x = *(const float4*)&sXB[i * 68 + k];
          acc += x.x * w1[k] + x.y * w1[k + 1] + x.z * w1[k + 2] + x.w * w1[k + 3];
        }
        sZ1[i * 276 + offn] = acc;
      }
    } else {
      float acc = 0.f;
#pragma unroll
      for (int k = 0; k < 64; k += 4) {
        float4 c = *(const float4*)&sXC[ia * 68 + k];
        float4 x = *(const float4*)&sXB[ja * 68 + k];
        acc += c.x * x.x + c.y * x.y + c.z * x.z + c.w * x.w;
      }
      sA1[ia * 16 + ja] = (ja <= ia) ? acc : 0.f;
    }
    __syncthreads();

    // ---- P2: A: z1b_pre = XC@W1 (regs) | B: Z2 quad+butterfly -> sg2 ----
    if (isA) {
#pragma unroll
      for (int i = 0; i < 16; ++i) {
        float acc = 0.f;
#pragma unroll
        for (int k = 0; k < 64; k += 4) {
          float4 x = *(const float4*)&sXC[i * 68 + k];
          acc += x.x * w1[k] + x.y * w1[k + 1] + x.z * w1[k + 2] + x.w * w1[k + 3];
        }
        z1bR[i] = acc;
      }
    } else {
#pragma unroll
      for (int i = 0; i < 16; ++i) {
        float acc = 0.f;
#pragma unroll
        for (int kk = 0; kk < 64; kk += 4) {
          float4 z = *(const float4*)&sZ1[i * 276 + q * 68 + kk];
          acc += z.x * w2c[kk] + z.y * w2c[kk + 1] + z.z * w2c[kk + 2] + z.w * w2c[kk + 3];
        }
        acc += __shfl_xor(acc, 16, 64);
        acc += __shfl_xor(acc, 32, 64);
        if (q == (i >> 2))
          sg2[i * 64 + m] = acc - sBIG[256 + i * 64 + m];
      }
    }
    __syncthreads();

    // ---- P3: A: stage XC(nc+1) | B: g1 = g2@W2^T -> sBIG ----------------
    if (isA) {
      *(float4*)&sXC[prow * 68 + pcol] = xcP;
    } else {
#pragma unroll
      for (int i = 0; i < 16; ++i) {
        float acc = 0.f;
#pragma unroll
        for (int mm = 0; mm < 64; mm += 4) {
          float4 g = *(const float4*)&sg2[i * 64 + mm];
          acc += g.x * w2r[mm] + g.y * w2r[mm + 1] + g.z * w2r[mm + 2] + g.w * w2r[mm + 3];
        }
        sBIG[i * 256 + n] = acc;
      }
    }
    __syncthreads();

    // ---- P4: A: Z1b finalize -> sZ1b, W1 update | B: W2 row update ------
    {
      const float cl = sCo[15];
      if (isA) {
        float g1R[16];
#pragma unroll
        for (int j = 0; j < 16; ++j) g1R[j] = sBIG[j * 256 + n];
#pragma unroll
        for (int i = 0; i < 16; ++i) {
          float at = 0.f;
#pragma unroll
          for (int j = 0; j < 16; ++j)
            if (j <= i) at += sA1[i * 16 + j] * g1R[j];
          sZ1b[i * 272 + offn] = z1bR[i] - sCo[i] * at;
        }
#pragma unroll
        for (int i = 0; i < 16; ++i) {
          const float s = cl * g1R[i];
#pragma unroll
          for (int k = 0; k < 64; k += 4) {
            float4 x = *(const float4*)&sXB[i * 68 + k];
            w1[k]     -= s * x.x; w1[k + 1] -= s * x.y;
            w1[k + 2] -= s * x.z; w1[k + 3] -= s * x.w;
          }
        }
      } else {
#pragma unroll
        for (int i = 0; i < 16; ++i) {
          const float s = cl * sZ1[i * 276 + offn];
#pragma unroll
          for (int mm = 0; mm < 64; mm += 4) {
            float4 g = *(const float4*)&sg2[i * 64 + mm];
            w2r[mm]     -= s * g.x; w2r[mm + 1] -= s * g.y;
            w2r[mm + 2] -= s * g.z; w2r[mm + 3] -= s * g.w;
          }
        }
      }
    }
    __syncthreads();

    // ---- P5: A: Attn2 -> sBIG[0,256), stage XB/XA(nc+1) | B: Z2b pre ----
    if (isA) {
      float acc = 0.f;
#pragma unroll
      for (int kk = 0; kk < 256; kk += 4) {
        const int koff = ((kk >> 6) * 68) + (kk & 63);
        float4 a = *(const float4*)&sZ1b[ia * 272 + koff];
        float4 z = *(const float4*)&sZ1[ja * 276 + koff];
        acc += a.x * z.x + a.y * z.y + a.z * z.z + a.w * z.w;
      }
      sBIG[ia * 16 + ja] = (ja <= ia) ? acc : 0.f;
      *(float4*)&sXB[prow * 68 + pcol] = xbP;
      *(float4*)&sBIG[256 + prow * 64 + pcol] = xaP;
    } else {
#pragma unroll
      for (int i = 0; i < 16; ++i) {
        float acc = 0.f;
#pragma unroll
        for (int kk = 0; kk < 64; kk += 4) {
          float4 z = *(const float4*)&sZ1b[i * 272 + q * 68 + kk];
          acc += z.x * w2c[kk] + z.y * w2c[kk + 1] + z.z * w2c[kk + 2] + z.w * w2c[kk + 3];
        }
        acc += __shfl_xor(acc, 16, 64);
        acc += __shfl_xor(acc, 32, 64);
        z2bF[i] = acc;
      }
    }
    __syncthreads();

    // ---- P6: B: Z2b finalize + store, W2 col update ----------------------
    if (!isA) {
      const float cl = sCo[15];
#pragma unroll
      for (int i = 0; i < 16; ++i) {
        float at = 0.f;
#pragma unroll
        for (int j = 0; j < 16; ++j) at += sBIG[i * 16 + j] * sg2[j * 64 + m];
        const float ov = z2bF[i] - sCo[i] * at;
        if (q == 0) Out[cb + i * 1024 + m] = ov;
      }
#pragma unroll
      for (int i = 0; i < 16; ++i) {
        const float s = cl * sg2[i * 64 + m];
#pragma unroll
        for (int kk = 0; kk < 64; kk += 4) {
          float4 z = *(const float4*)&sZ1[i * 276 + q * 68 + kk];
          w2c[kk]     -= s * z.x; w2c[kk + 1] -= s * z.y;
          w2c[kk + 2] -= s * z.z; w2c[kk + 3] -= s * z.w;
        }
      }
    }
    __syncthreads();
  }
}

// ---------------------------------------------------------------------------
// Workspace (fp32 floats): bXC [0,16.7M) | bXB [16.7M,33.5M) | bZ2b
// [33.5M,50.3M) | bCo [50.3M,+262k).  193 MiB.  XA (V proj) lives in d_out
// until the final GEMM overwrites it (stream-ordered, safe).
// ---------------------------------------------------------------------------
extern "C" void kernel_launch(void* const* d_in, const int* in_sizes, int n_in,
                              void* d_out, int out_size, void* d_ws, size_t ws_size,
                              hipStream_t stream)
{
  const float* H    = (const float*)d_in[0];
  const float* Wq   = (const float*)d_in[1];
  const float* Wk   = (const float*)d_in[2];
  const float* Wv   = (const float*)d_in[3];
  const float* Wo   = (const float*)d_in[4];
  const float* Wil  = (const float*)d_in[5];
  const float* bil  = (const float*)d_in[6];
  const float* W1   = (const float*)d_in[7];
  const float* W2   = (const float*)d_in[8];
  float* out        = (float*)d_out;

  float* ws    = (float*)d_ws;
  float* bXC   = ws;
  float* bXB   = ws + 16777216;
  float* bZ2b  = ws + 33554432;
  float* bCo   = ws + 50331648;
  float* bXA   = out;

  const int M = Bsz * Lsz, N = Csz, K = Csz;
  dim3 gg(N / 64, M / 64);
  dim3 bb(256);

  gemm64<<<gg, bb, 0, stream>>>(H, Wq, bXC, M, N, K);
  gemm64<<<gg, bb, 0, stream>>>(H, Wk, bXB, M, N, K);
  gemm64<<<gg, bb, 0, stream>>>(H, Wv, bXA, M, N, K);
  ilr_coeff<<<M / 4, 256, 0, stream>>>(H, Wil, bil, bCo);
  ttt_scan<<<Bsz * NHsz, 512, 0, stream>>>(bXA, bXB, bXC, bCo, W1, W2, bZ2b);
  gemm64<<<gg, bb, 0, stream>>>(bZ2b, Wo, out, M, N, K);
}